// Round 5
// baseline (632.499 us; speedup 1.0000x reference)
//
#include <hip/hip_runtime.h>
#include <hip/hip_bf16.h>
#include <stdint.h>

typedef __attribute__((ext_vector_type(8))) short short8;
typedef __attribute__((ext_vector_type(4))) float f32x4;

#define DEVI __device__ __forceinline__

DEVI unsigned short f2bf(float f) {
  union { float f; unsigned int u; } c; c.f = f;
  unsigned int u = c.u;
  u += 0x7fffu + ((u >> 16) & 1u);   // round-to-nearest-even
  return (unsigned short)(u >> 16);
}

DEVI void gl_lds16(const void* gsrc, void* lds) {
  __builtin_amdgcn_global_load_lds(
      (const __attribute__((address_space(1))) unsigned int*)gsrc,
      (__attribute__((address_space(3))) unsigned int*)lds, 16, 0, 0);
}

#define MFMA(a, b, c) __builtin_amdgcn_mfma_f32_16x16x32_bf16((a), (b), (c), 0, 0, 0)

// ---------------- fp32 -> bf16 convert (vectorized) ----------------
__global__ void cvt_f32_bf16(const float* __restrict__ in,
                             unsigned short* __restrict__ out, int n4) {
  const int stride = gridDim.x * blockDim.x;
  for (int i = blockIdx.x * blockDim.x + threadIdx.x; i < n4; i += stride) {
    const float4 v = ((const float4*)in)[i];
    ushort4 o;
    o.x = f2bf(v.x); o.y = f2bf(v.y); o.z = f2bf(v.z); o.w = f2bf(v.w);
    ((ushort4*)out)[i] = o;
  }
}

// Fragment-packed layouts (per head, T=2048, HD=128, 262144 elems):
//  QK-pack:  off(t,e) = (t>>4)*2048 + (e>>5)*512 + (t&15)*32 + (e&31)
//  V-pack:   off(d,t) = (t>>6)*8192 + (d>>4)*1024 + ((t>>5)&1)*512 + (d&15)*32 + (t&31)

// ---------------- 256x256 fine-phased bf16 GEMM ----------------
// C[M,N] = A[M,K] * Bw[N,K]^T + bias.
// MODE 0: fused QKV (N=6144). MODE 3: fp32 row-major C.
// 8 waves (2M x 4N), per-wave 128x64 out, BK=32, 4-deep LDS ring,
// 4 phases per K-tile with one-phase register lookahead, counted vmcnt
// (8/4/0 tiers, never 0 in steady state), frag-packed LDS (0 conflicts).
template<int MODE>
__global__ __launch_bounds__(512, 2)
void gemm256(const unsigned short* __restrict__ A,
             const unsigned short* __restrict__ Bw,
             const float* __restrict__ bq,
             const float* __restrict__ bk,
             const float* __restrict__ bv,
             float* __restrict__ Kf,
             float* __restrict__ Vf,
             unsigned short* __restrict__ Qpk,
             unsigned short* __restrict__ Kpk,
             unsigned short* __restrict__ Vpk,
             float* __restrict__ Cf,
             int M, int N, int K)
{
  __shared__ unsigned short S[4][16384];   // per slot: A frags [0,8192), B frags [8192,16384)
  const int tid  = threadIdx.x;
  const int lane = tid & 63;
  const int wid  = tid >> 6;
  const int l15  = lane & 15, l4 = lane >> 4;

  // XCD-bijective chunked swizzle.
  const int chunk = gridDim.x >> 3;
  const int q  = blockIdx.x;
  const int wg = (q & 7) * chunk + (q >> 3);
  const int bm = (wg & 31) * 256;
  const int bn = (wg >> 5) * 256;

  // staging: wave wid stages frags wid and wid+8 of A and B; lane l supplies
  // row (frag*16 + l&15), k-seg (l>>4)*8 -> LDS frag*1024B + lane*16B.
  const unsigned short* Asrc0 = A  + (size_t)(bm + wid * 16 + l15) * K + l4 * 8;
  const unsigned short* Asrc1 = A  + (size_t)(bm + (wid + 8) * 16 + l15) * K + l4 * 8;
  const unsigned short* Bsrc0 = Bw + (size_t)(bn + wid * 16 + l15) * K + l4 * 8;
  const unsigned short* Bsrc1 = Bw + (size_t)(bn + (wid + 8) * 16 + l15) * K + l4 * 8;

  const int nt = K >> 5;                    // K-tiles of 32
  // prologue: stage tiles 0,1,2 (A,A,B,B each = 4 loads/thread/tile)
#pragma unroll
  for (int kt = 0; kt < 3; ++kt) {
    unsigned short* Sd = S[kt];
    const int koff = kt * 32;
    gl_lds16(Asrc0 + koff, &Sd[wid * 512 + lane * 8]);
    gl_lds16(Asrc1 + koff, &Sd[(wid + 8) * 512 + lane * 8]);
    gl_lds16(Bsrc0 + koff, &Sd[8192 + wid * 512 + lane * 8]);
    gl_lds16(Bsrc1 + koff, &Sd[8192 + (wid + 8) * 512 + lane * 8]);
  }

  f32x4 acc[8][4] = {};
  const int mwave = wid >> 2, nwave = wid & 3;
  const int abase = mwave * 4096 + lane * 8;          // A frag 0 (mh0), elems
  const int bbase = 8192 + nwave * 2048 + lane * 8;   // B frag 0 (nh0)
  short8 afA[4], afB[4], bf0[2], bf1[2];

  // wait tile 0 landed (8 outstanding = tiles 1,2), preload ph0 regs
  asm volatile("s_waitcnt vmcnt(8)" ::: "memory");
  __builtin_amdgcn_s_barrier();
  {
    const unsigned short* Sb = S[0];
#pragma unroll
    for (int i = 0; i < 4; ++i) afA[i] = *(const short8*)&Sb[abase + i * 512];
#pragma unroll
    for (int j = 0; j < 2; ++j) bf0[j] = *(const short8*)&Sb[bbase + j * 512];
  }

  for (int kt = 0; kt < nt; ++kt) {
    const unsigned short* Sb = S[kt & 3];
    unsigned short* Sd = S[(kt + 3) & 3];
    const bool st = (kt + 3) < nt;
    const int koff = (kt + 3) * 32;

    // ---- phase 0: stage A-pair | read bf1 | MFMA (mh0,nh0) ----
    if (st) {
      gl_lds16(Asrc0 + koff, &Sd[wid * 512 + lane * 8]);
      gl_lds16(Asrc1 + koff, &Sd[(wid + 8) * 512 + lane * 8]);
    }
#pragma unroll
    for (int j = 0; j < 2; ++j) bf1[j] = *(const short8*)&Sb[bbase + (2 + j) * 512];
    __builtin_amdgcn_s_setprio(1);
#pragma unroll
    for (int m = 0; m < 4; ++m)
#pragma unroll
      for (int n = 0; n < 2; ++n)
        acc[m][n] = MFMA(afA[m], bf0[n], acc[m][n]);
    __builtin_amdgcn_s_setprio(0);
    __builtin_amdgcn_s_barrier();

    // ---- phase 1: read afB | MFMA (mh0,nh1) ----
#pragma unroll
    for (int i = 0; i < 4; ++i) afB[i] = *(const short8*)&Sb[abase + (4 + i) * 512];
    __builtin_amdgcn_s_setprio(1);
#pragma unroll
    for (int m = 0; m < 4; ++m)
#pragma unroll
      for (int n = 0; n < 2; ++n)
        acc[m][2 + n] = MFMA(afA[m], bf1[n], acc[m][2 + n]);
    __builtin_amdgcn_s_setprio(0);
    __builtin_amdgcn_s_barrier();

    // ---- phase 2: stage B-pair | MFMA (mh1,nh0) ----
    if (st) {
      gl_lds16(Bsrc0 + koff, &Sd[8192 + wid * 512 + lane * 8]);
      gl_lds16(Bsrc1 + koff, &Sd[8192 + (wid + 8) * 512 + lane * 8]);
    }
    __builtin_amdgcn_s_setprio(1);
#pragma unroll
    for (int m = 0; m < 4; ++m)
#pragma unroll
      for (int n = 0; n < 2; ++n)
        acc[4 + m][n] = MFMA(afB[m], bf0[n], acc[4 + m][n]);
    __builtin_amdgcn_s_setprio(0);
    __builtin_amdgcn_s_barrier();

    // ---- phase 3: counted vmcnt | read next afA/bf0 | MFMA (mh1,nh1) ----
    if (kt + 1 < nt) {
      if (kt < nt - 3)       asm volatile("s_waitcnt vmcnt(8)" ::: "memory");
      else if (kt == nt - 3) asm volatile("s_waitcnt vmcnt(4)" ::: "memory");
      else                   asm volatile("s_waitcnt vmcnt(0)" ::: "memory");
      __builtin_amdgcn_s_barrier();
      const unsigned short* Sn = S[(kt + 1) & 3];
#pragma unroll
      for (int i = 0; i < 4; ++i) afA[i] = *(const short8*)&Sn[abase + i * 512];
#pragma unroll
      for (int j = 0; j < 2; ++j) bf0[j] = *(const short8*)&Sn[bbase + j * 512];
    }
    __builtin_amdgcn_s_setprio(1);
#pragma unroll
    for (int m = 0; m < 4; ++m)
#pragma unroll
      for (int n = 0; n < 2; ++n)
        acc[4 + m][2 + n] = MFMA(afB[m], bf1[n], acc[4 + m][2 + n]);
    __builtin_amdgcn_s_setprio(0);
    // no iteration-end barrier needed: next overwrite of any slot is
    // >=2 barriers away from its last read (slot-lifetime audit).
  }

  // ---- epilogue ----
  const int rbase = l4 * 4;
#pragma unroll
  for (int m = 0; m < 8; ++m) {
    const int row0 = bm + (wid >> 2) * 128 + m * 16 + rbase;
#pragma unroll
    for (int n = 0; n < 4; ++n) {
      const int col6 = bn + (wid & 3) * 64 + n * 16 + l15;
      if constexpr (MODE == 3) {
        const float bb = bq[col6];
#pragma unroll
        for (int r = 0; r < 4; ++r)
          Cf[(size_t)(row0 + r) * N + col6] = acc[m][n][r] + bb;
      } else {
        const int sel = col6 >> 11;
        const int col = col6 & 2047;
        const float bb = (sel == 0 ? bq : sel == 1 ? bk : bv)[col];
        float vv[4];
#pragma unroll
        for (int r = 0; r < 4; ++r) vv[r] = acc[m][n][r] + bb;
        const int bI = row0 >> 11, t0 = row0 & 2047;
        const int h = col >> 7, e = col & 127;
        const size_t hb = ((size_t)(bI * 16 + h)) * 262144;
        if (sel == 0) {
          const size_t qb = hb + (size_t)(t0 >> 4) * 2048 + (e >> 5) * 512
                          + (t0 & 15) * 32 + (e & 31);
#pragma unroll
          for (int r = 0; r < 4; ++r) Qpk[qb + (size_t)r * 32] = f2bf(vv[r]);
        } else if (sel == 1) {
          const size_t idx = hb + (size_t)t0 * 128 + e;
          const size_t qb = hb + (size_t)(t0 >> 4) * 2048 + (e >> 5) * 512
                          + (t0 & 15) * 32 + (e & 31);
#pragma unroll
          for (int r = 0; r < 4; ++r) {
            Kf[idx + (size_t)r * 128] = vv[r];
            Kpk[qb + (size_t)r * 32] = f2bf(vv[r]);
          }
        } else {
          const size_t idx = hb + (size_t)t0 * 128 + e;
#pragma unroll
          for (int r = 0; r < 4; ++r) Vf[idx + (size_t)r * 128] = vv[r];
          const size_t vb = hb + (size_t)(t0 >> 6) * 8192 + (size_t)(e >> 4) * 1024
                          + ((t0 >> 5) & 1) * 512 + (e & 15) * 32 + (t0 & 31);
          ushort4 pk;
          pk.x = f2bf(vv[0]); pk.y = f2bf(vv[1]);
          pk.z = f2bf(vv[2]); pk.w = f2bf(vv[3]);
          *(ushort4*)&Vpk[vb] = pk;
        }
      }
    }
  }
}

// ---------------- causal flash attention, barrier-free ----------------
__global__ __launch_bounds__(64, 2)
void attn_fwd(const unsigned short* __restrict__ Qf,
              const unsigned short* __restrict__ Kf,
              const unsigned short* __restrict__ Vf,
              unsigned short* __restrict__ Ab)
{
  constexpr float scale = 0.08838834764831843f;  // 1/sqrt(128)
  __shared__ unsigned short Pl[32][72];

  const int bid = blockIdx.x;
  const int sw  = (bid & 7) * 512 + (bid >> 3);
  const int bh  = sw >> 6;
  const int qi  = 63 - (sw & 63);
  const int qw  = qi * 32;
  const int bI = bh >> 4, h = bh & 15;
  const int lane = threadIdx.x;
  const int lr = lane & 15, lg = lane >> 4;
  const int lfo = lr * 32 + lg * 8;

  const unsigned short* Qp = Qf + (size_t)bh * 262144 + (size_t)(qw >> 4) * 2048;
  const unsigned short* Kp = Kf + (size_t)bh * 262144;
  const unsigned short* Vp = Vf + (size_t)bh * 262144;

  short8 qf[2][4];
#pragma unroll
  for (int m = 0; m < 2; ++m)
#pragma unroll
    for (int ks = 0; ks < 4; ++ks)
      qf[m][ks] = *(const short8*)&Qp[m * 2048 + ks * 512 + lfo];

  f32x4 o[2][8] = {};
  float mrun[2][4], lrun[2][4];
#pragma unroll
  for (int m = 0; m < 2; ++m)
#pragma unroll
    for (int r = 0; r < 4; ++r) { mrun[m][r] = -1e30f; lrun[m][r] = 0.f; }

  const int nfull = qw >> 6;
  for (int kt = 0; kt <= nfull; ++kt) {
    const int kv0 = kt * 64;
    const bool diag = (kt == nfull);
    const unsigned short* Kt = Kp + (size_t)(kv0 >> 4) * 2048;
    const unsigned short* Vt = Vp + (size_t)(kv0 >> 6) * 8192;

    short8 kf[4][4];
#pragma unroll
    for (int n = 0; n < 4; ++n)
#pragma unroll
      for (int ks = 0; ks < 4; ++ks)
        kf[n][ks] = *(const short8*)&Kt[n * 2048 + ks * 512 + lfo];
    f32x4 s[2][4] = {};
#pragma unroll
    for (int ks = 0; ks < 4; ++ks)
#pragma unroll
      for (int m = 0; m < 2; ++m)
#pragma unroll
        for (int n = 0; n < 4; ++n)
          s[m][n] = MFMA(qf[m][ks], kf[n][ks], s[m][n]);

    short8 vf[2][8];
#pragma unroll
    for (int ks2 = 0; ks2 < 2; ++ks2)
#pragma unroll
      for (int dt = 0; dt < 8; ++dt)
        vf[ks2][dt] = *(const short8*)&Vt[dt * 1024 + ks2 * 512 + lfo];

    float tmax[2][4];
#pragma unroll
    for (int m = 0; m < 2; ++m)
#pragma unroll
      for (int r = 0; r < 4; ++r) tmax[m][r] = -1e30f;
#pragma unroll
    for (int m = 0; m < 2; ++m)
#pragma unroll
      for (int n = 0; n < 4; ++n) {
        const int kg = kv0 + n * 16 + lr;
#pragma unroll
        for (int r = 0; r < 4; ++r) {
          float sv = s[m][n][r] * scale;
          if (diag) {
            const int qg = qw + m * 16 + lg * 4 + r;
            sv = (kg <= qg) ? sv : -1e30f;
          }
          s[m][n][r] = sv;
          tmax[m][r] = fmaxf(tmax[m][r], sv);
        }
      }
#pragma unroll
    for (int m = 0; m < 2; ++m)
#pragma unroll
      for (int r = 0; r < 4; ++r) {
#pragma unroll
        for (int off = 8; off >= 1; off >>= 1)
          tmax[m][r] = fmaxf(tmax[m][r], __shfl_xor(tmax[m][r], off));
        const float mnew  = fmaxf(mrun[m][r], tmax[m][r]);
        const float alpha = __expf(mrun[m][r] - mnew);
        mrun[m][r] = mnew;
        lrun[m][r] *= alpha;
#pragma unroll
        for (int d = 0; d < 8; ++d) o[m][d][r] *= alpha;
      }
#pragma unroll
    for (int m = 0; m < 2; ++m) {
      float ls[4] = {0.f, 0.f, 0.f, 0.f};
#pragma unroll
      for (int n = 0; n < 4; ++n)
#pragma unroll
        for (int r = 0; r < 4; ++r) {
          const float p = __expf(s[m][n][r] - mrun[m][r]);
          s[m][n][r] = p;
          ls[r] += p;
        }
#pragma unroll
      for (int r = 0; r < 4; ++r) {
#pragma unroll
        for (int off = 8; off >= 1; off >>= 1) ls[r] += __shfl_xor(ls[r], off);
        lrun[m][r] += ls[r];
      }
#pragma unroll
      for (int n = 0; n < 4; ++n)
#pragma unroll
        for (int r = 0; r < 4; ++r)
          Pl[m * 16 + lg * 4 + r][n * 16 + lr] = f2bf(s[m][n][r]);
    }
#pragma unroll
    for (int ks2 = 0; ks2 < 2; ++ks2) {
      short8 pa[2];
#pragma unroll
      for (int m = 0; m < 2; ++m)
        pa[m] = *(const short8*)&Pl[m * 16 + lr][ks2 * 32 + lg * 8];
#pragma unroll
      for (int dt = 0; dt < 8; ++dt)
#pragma unroll
        for (int m = 0; m < 2; ++m)
          o[m][dt] = MFMA(pa[m], vf[ks2][dt], o[m][dt]);
    }
  }
#pragma unroll
  for (int m = 0; m < 2; ++m)
#pragma unroll
    for (int r = 0; r < 4; ++r) {
      const float inv = 1.0f / lrun[m][r];
      const int t = qw + m * 16 + lg * 4 + r;
      unsigned short* dst = Ab + ((size_t)(bI * 2048 + t)) * 2048 + h * 128;
#pragma unroll
      for (int dt = 0; dt < 8; ++dt)
        dst[dt * 16 + lr] = f2bf(o[m][dt][r] * inv);
    }
}

extern "C" void kernel_launch(void* const* d_in, const int* in_sizes, int n_in,
                              void* d_out, int out_size, void* d_ws, size_t ws_size,
                              hipStream_t stream) {
  const float* x  = (const float*)d_in[0];
  const float* wq = (const float*)d_in[1];
  const float* bq = (const float*)d_in[2];
  const float* wk = (const float*)d_in[3];
  const float* bk = (const float*)d_in[4];
  const float* wv = (const float*)d_in[5];
  const float* bv = (const float*)d_in[6];
  const float* wo = (const float*)d_in[7];
  const float* bo = (const float*)d_in[8];

  float* out  = (float*)d_out;                 // [B,T,d] fp32
  float* kout = out + (size_t)16777216;        // [B,H,T,hd] fp32
  float* vout = out + (size_t)33554432;        // [B,H,T,hd] fp32

  // workspace layout (bf16 elements)
  unsigned short* xb  = (unsigned short*)d_ws;       // x bf16 [8192,2048]
  unsigned short* wqb = xb  + 16777216;              // wq/wk/wv contiguous = [6144,2048]
  unsigned short* wkb = wqb + 4194304;
  unsigned short* wvb = wkb + 4194304;
  unsigned short* wob = wvb + 4194304;
  unsigned short* Qw  = wob + 4194304;               // Q bf16 fragment-packed
  unsigned short* Kw  = Qw  + 16777216;              // K bf16 fragment-packed
  unsigned short* Vfw = Kw  + 16777216;              // V bf16 V-packed
  unsigned short* Aw  = Vfw + 16777216;              // attn out bf16 [B*T, 2048]

  const int M = 8192, K = 2048;

  cvt_f32_bf16<<<1024, 256, 0, stream>>>(x,  xb,  4194304);
  cvt_f32_bf16<<<256,  256, 0, stream>>>(wq, wqb, 1048576);
  cvt_f32_bf16<<<256,  256, 0, stream>>>(wk, wkb, 1048576);
  cvt_f32_bf16<<<256,  256, 0, stream>>>(wv, wvb, 1048576);
  cvt_f32_bf16<<<256,  256, 0, stream>>>(wo, wob, 1048576);

  // fused QKV: N = 6144, 24x32 = 768 blocks
  gemm256<0><<<dim3(768), 512, 0, stream>>>(xb, wqb, bq, bk, bv,
                                            kout, vout, Qw, Kw, Vfw,
                                            nullptr, M, 6144, K);

  attn_fwd<<<dim3(4096), 64, 0, stream>>>(Qw, Kw, Vfw, Aw);

  // out projection: N = 2048, 8x32 = 256 blocks
  gemm256<3><<<dim3(256), 512, 0, stream>>>(Aw, wob, bo, nullptr, nullptr,
                                            nullptr, nullptr, nullptr, nullptr, nullptr,
                                            out, M, 2048, K);
}